// Round 6
// baseline (241.889 us; speedup 1.0000x reference)
//
#include <hip/hip_runtime.h>

#define HDIM 256
#define CSBLK 2048           // colsum blocks (divisible by NREP)
#define RDBLK 2048           // rowdot blocks
#define NREP 8               // XCD replicas (blockIdx&7 ~ XCD under round-robin dispatch)
#define PADQ 16              // u64 slots per accumulator entry = 128B line padding
#define FXSCALE 16777216.0   // 2^24 fixed point (deterministic integer accumulation)

// ---------------- Stage 0: zero counts8 | acc64 | tickets (one contiguous region) ----
__global__ void k_zero(uint4* __restrict__ p, int n4) {
    int i = blockIdx.x * blockDim.x + threadIdx.x;
    if (i < n4) p[i] = make_uint4(0u, 0u, 0u, 0u);
}

// ---------------- Stage 1: 8-replica histogram of src indices ------------------------
__global__ void k_count(const int4* __restrict__ src4, const int* __restrict__ src,
                        int E, int N, unsigned int* __restrict__ counts8) {
    int i = blockIdx.x * blockDim.x + threadIdx.x;
    unsigned int* c = counts8 + (size_t)(blockIdx.x & (NREP - 1)) * N;
    int E4 = E >> 2;
    if (i < E4) {
        int4 v = src4[i];
        atomicAdd(&c[v.x], 1u); atomicAdd(&c[v.y], 1u);
        atomicAdd(&c[v.z], 1u); atomicAdd(&c[v.w], 1u);
    }
    if (i < (E & 3)) {
        atomicAdd(&counts8[src[(E4 << 2) + i]], 1u);
    }
}

// ---------------- Stage 2 (fused): weighted colsum -> fixed-point atomics -> matvec ---
// 2048 blocks x 256 thr = 32 waves/CU. Unroll-2 dual accumulators for MLP (round-5
// lesson: 1 row-body in flight => latency-bound at 1.5 TB/s).
// Epilogue: per-block LDS reduce -> ONE u64 atomicAdd per h into an XCD-local,
// 128B-padded accumulator (256 adds/line, L2-local). Hierarchical ticket; last
// block converts fixed-point -> ls and computes v = R @ ls.
__global__ __launch_bounds__(256)
void k_colsum_mv(const float4* __restrict__ x4,
                 const unsigned int* __restrict__ counts8, int N,
                 const float* __restrict__ Rm,
                 unsigned long long* __restrict__ acc64,
                 unsigned int* __restrict__ tick,
                 float* __restrict__ v) {
    const int colgrp = threadIdx.x & 63;
    const int rowOff = threadIdx.x >> 6;
    const int rep = blockIdx.x & (NREP - 1);
    const int stride = CSBLK * 4;

    float4 a0 = make_float4(0.f, 0.f, 0.f, 0.f);
    float4 a1 = make_float4(0.f, 0.f, 0.f, 0.f);
    int n = blockIdx.x * 4 + rowOff;

#define CS_BODY(NN, ACC) {                                                        \
        float c = 0.f;                                                            \
        _Pragma("unroll")                                                         \
        for (int r = 0; r < NREP; ++r) c += (float)counts8[(size_t)r * N + (NN)]; \
        float4 x = x4[(size_t)(NN) * 64 + colgrp];                                \
        ACC.x += c * x.x; ACC.y += c * x.y; ACC.z += c * x.z; ACC.w += c * x.w; }

    for (; n + stride < N; n += 2 * stride) {
        CS_BODY(n, a0);
        CS_BODY(n + stride, a1);
    }
    for (; n < N; n += stride) CS_BODY(n, a0);
#undef CS_BODY
    a0.x += a1.x; a0.y += a1.y; a0.z += a1.z; a0.w += a1.w;

    __shared__ float s[4 * HDIM];
    int col = colgrp * 4;
    s[rowOff * HDIM + col + 0] = a0.x;
    s[rowOff * HDIM + col + 1] = a0.y;
    s[rowOff * HDIM + col + 2] = a0.z;
    s[rowOff * HDIM + col + 3] = a0.w;
    __syncthreads();
    const int tid = threadIdx.x;
    float part = s[tid] + s[HDIM + tid] + s[2 * HDIM + tid] + s[3 * HDIM + tid];

    // Deterministic fixed-point accumulate: one padded-line atomic per (rep,h).
    long long q = llrint((double)part * FXSCALE);
    atomicAdd(&acc64[(size_t)(rep * HDIM + tid) * PADQ], (unsigned long long)q);
    __threadfence();
    __syncthreads();

    __shared__ unsigned int lastflag;
    if (tid == 0) {
        lastflag = 0u;
        if (atomicAdd(&tick[rep * 32], 1u) == (CSBLK / NREP - 1)) {      // last of replica
            if (atomicAdd(&tick[NREP * 32], 1u) == NREP - 1) lastflag = 1u; // last overall
        }
    }
    __syncthreads();

    if (lastflag) {
        __threadfence();
        __shared__ float lss[HDIM];
        long long qs = 0;
        #pragma unroll
        for (int r = 0; r < NREP; ++r)
            qs += (long long)atomicAdd(&acc64[(size_t)(r * HDIM + tid) * PADQ], 0ull);
        lss[tid] = (float)((double)qs * (1.0 / FXSCALE));
        __syncthreads();
        const float4* R4 = (const float4*)(Rm + (size_t)tid * HDIM);
        float a = 0.f;
        #pragma unroll 8
        for (int j = 0; j < 64; ++j) {
            float4 r = R4[j];
            a += r.x * lss[4 * j] + r.y * lss[4 * j + 1] + r.z * lss[4 * j + 2] + r.w * lss[4 * j + 3];
        }
        v[tid] = a;
    }
}

// ---------------- Stage 3: t[n] = dot(x_trg[n], v). Wave-per-row, grid-stride, unroll-2.
__global__ __launch_bounds__(256)
void k_rowdot(const float4* __restrict__ x4, const float* __restrict__ v,
              int N, float* __restrict__ t) {
    const int lane = threadIdx.x & 63;
    const float4 vv = ((const float4*)v)[lane];        // per-lane slice of v, L2 hit
    const int nw = (gridDim.x * blockDim.x) >> 6;      // total waves
    int n = (blockIdx.x * blockDim.x + threadIdx.x) >> 6;

    for (; n + nw < N; n += 2 * nw) {
        float4 xa = x4[(size_t)n * 64 + lane];
        float4 xb = x4[(size_t)(n + nw) * 64 + lane];
        float da = xa.x * vv.x + xa.y * vv.y + xa.z * vv.z + xa.w * vv.w;
        float db = xb.x * vv.x + xb.y * vv.y + xb.z * vv.z + xb.w * vv.w;
        #pragma unroll
        for (int off = 32; off > 0; off >>= 1) {
            da += __shfl_down(da, off, 64);
            db += __shfl_down(db, off, 64);
        }
        if (lane == 0) { t[n] = da; t[n + nw] = db; }
    }
    if (n < N) {
        float4 xa = x4[(size_t)n * 64 + lane];
        float da = xa.x * vv.x + xa.y * vv.y + xa.z * vv.z + xa.w * vv.w;
        #pragma unroll
        for (int off = 32; off > 0; off >>= 1) da += __shfl_down(da, off, 64);
        if (lane == 0) t[n] = da;
    }
}

// ---------------- Stage 4: out[e] = t[trg[e]], vectorized ---------------------------
__global__ void k_gather(const int4* __restrict__ trg4, const int* __restrict__ trg, int E,
                         const float* __restrict__ t,
                         float4* __restrict__ out4, float* __restrict__ out) {
    int i = blockIdx.x * blockDim.x + threadIdx.x;
    int E4 = E >> 2;
    if (i < E4) {
        int4 v = trg4[i];
        out4[i] = make_float4(t[v.x], t[v.y], t[v.z], t[v.w]);
    }
    if (i < (E & 3)) {
        int e = (E4 << 2) + i;
        out[e] = t[trg[e]];
    }
}

extern "C" void kernel_launch(void* const* d_in, const int* in_sizes, int n_in,
                              void* d_out, int out_size, void* d_ws, size_t ws_size,
                              hipStream_t stream) {
    const float* x_src = (const float*)d_in[0];
    const float* x_trg = (const float*)d_in[1];
    const float* Rm    = (const float*)d_in[2];
    const int*   edge  = (const int*)d_in[3];   // [0..E)=src, [E..2E)=trg
    float* out = (float*)d_out;

    const int N_src = in_sizes[0] / HDIM;
    const int N_trg = in_sizes[1] / HDIM;
    const int E     = in_sizes[3] / 2;

    // ---- workspace layout (one contiguous zero-region, then v, t) ----
    char* ws = (char*)d_ws;
    const size_t counts_bytes = (size_t)NREP * N_src * sizeof(unsigned int);        // 1.6 MB
    const size_t acc_bytes    = (size_t)NREP * HDIM * PADQ * sizeof(unsigned long long); // 256 KB
    const size_t tick_bytes   = (size_t)(NREP * 32 + 32) * sizeof(unsigned int);    // per-rep + super
    size_t zbytes = counts_bytes + acc_bytes + tick_bytes;
    zbytes = (zbytes + 15) & ~(size_t)15;

    unsigned int* counts8 = (unsigned int*)ws;
    unsigned long long* acc64 = (unsigned long long*)(ws + counts_bytes);
    unsigned int* tick = (unsigned int*)(ws + counts_bytes + acc_bytes);
    float* v = (float*)(ws + ((zbytes + 255) & ~(size_t)255));
    float* t = v + HDIM;
    (void)ws_size; (void)n_in; (void)out_size;

    const int n4 = (int)(zbytes / 16);
    k_zero<<<(n4 + 255) / 256, 256, 0, stream>>>((uint4*)ws, n4);

    const int E4 = E >> 2;
    const int cntThreads = (E4 > 0 ? E4 : 1);
    k_count<<<(cntThreads + 255) / 256, 256, 0, stream>>>(
        (const int4*)edge, edge, E, N_src, counts8);

    k_colsum_mv<<<CSBLK, 256, 0, stream>>>(
        (const float4*)x_src, counts8, N_src, Rm, acc64, tick, v);

    k_rowdot<<<RDBLK, 256, 0, stream>>>((const float4*)x_trg, v, N_trg, t);

    k_gather<<<(cntThreads + 255) / 256, 256, 0, stream>>>(
        (const int4*)(edge + E), edge + E, E, t, (float4*)out, out);
}